// Round 5
// baseline (239.124 us; speedup 1.0000x reference)
//
#include <hip/hip_runtime.h>

#define NAG 16
#define SPB 8       // scenes per block
#define NBLK 1024   // 1024 * 8 = 8192 scenes; 4 blocks/CU fully resident
#define R2f 64.0f

typedef unsigned short u16;
typedef __attribute__((ext_vector_type(8))) short short8;
typedef __attribute__((ext_vector_type(4))) float f32x4;

#define MFMA(a, b, c) __builtin_amdgcn_mfma_f32_16x16x32_bf16(a, b, c, 0, 0, 0)

__device__ __forceinline__ u16 f2b(float f) {
    unsigned u = __float_as_uint(f);
    unsigned r = u + 0x7FFFu + ((u >> 16) & 1u);   // RNE
    return (u16)(r >> 16);
}

// A-fragment of W^T for output-channel tile `tile`, K-step `s` (32 input chans):
// element j <-> k = s*32 + q*8 + j, m = tile*16 + mrow; value = W[k][m] (W is [K][N] row-major)
__device__ __forceinline__ short8 load_wfrag(const float* __restrict__ W, int N,
                                             int tile, int s, int q, int mrow) {
    const float* p = W + (size_t)(s * 32 + q * 8) * N + tile * 16 + mrow;
    union { short8 v; unsigned u[4]; } r;
    #pragma unroll
    for (int jj = 0; jj < 4; ++jj) {
        const float f0 = p[(2 * jj) * N];
        const float f1 = p[(2 * jj + 1) * N];
        r.u[jj] = (unsigned)f2b(f0) | ((unsigned)f2b(f1) << 16);
    }
    return r.v;
}

// adjacency B-fragment: B[k][i], i = lane&15, k = q*8+j; adj[k][i] = bit k of mask[i]
// (adj symmetric). k >= 16 -> bits shift out -> exact 0.
__device__ __forceinline__ short8 make_adjB(unsigned m, int q) {
    union { short8 v; unsigned u[4]; } r;
    #pragma unroll
    for (int jj = 0; jj < 4; ++jj) {
        const int k0 = q * 8 + 2 * jj;              // <= 30
        const unsigned lo = ((m >> k0) & 1u) ? 0x3F80u : 0u;        // bf16 1.0
        const unsigned hi = ((m >> (k0 + 1)) & 1u) ? 0x3F80u : 0u;
        r.u[jj] = lo | (hi << 16);
    }
    return r.v;
}

__device__ __forceinline__ void relu_store4(u16* d, f32x4 a) {
    const unsigned p0 = (unsigned)f2b(fmaxf(a[0], 0.f)) | ((unsigned)f2b(fmaxf(a[1], 0.f)) << 16);
    const unsigned p1 = (unsigned)f2b(fmaxf(a[2], 0.f)) | ((unsigned)f2b(fmaxf(a[3], 0.f)) << 16);
    uint2 u; u.x = p0; u.y = p1;
    *(uint2*)d = u;   // 8B-aligned by construction at call sites
}

__global__ __launch_bounds__(256, 4) void gnn_fused2(
    const float* __restrict__ x, const float* __restrict__ pos,
    const float* __restrict__ Wrel1, const float* __restrict__ brel1,
    const float* __restrict__ Wroot1,
    const float* __restrict__ Wrel2, const float* __restrict__ brel2,
    const float* __restrict__ Wroot2,
    const float* __restrict__ Wh1, const float* __restrict__ bh1,
    const float* __restrict__ Wh2, const float* __restrict__ bh2,
    const float* __restrict__ Wh3, const float* __restrict__ bh3,
    float* __restrict__ out)
{
    // padded row strides: +8 u16 (16B) keeps b128 rows on distinct bank groups
    __shared__ __align__(16) u16 xb[16 * 72];     // x   [agent][ch0..63]
    __shared__ __align__(16) u16 yT[128 * 40];    // y^T [channel][agent0..15 | 16..31 = zero pad]
    __shared__ __align__(16) u16 x1b[16 * 136];   // x1  [agent][ch0..127]
    __shared__ __align__(16) u16 x2b[16 * 136];   // x2
    __shared__ __align__(16) u16 h1b[16 * 72];    // h1  [agent][ch0..63]
    __shared__ __align__(16) u16 h2b[16 * 40];    // h2  [agent][ch0..31]
    __shared__ unsigned mask[NAG];

    const int t = threadIdx.x;
    const int wv = t >> 6;
    const int lane = t & 63;
    const int mrow = lane & 15;
    const int q = lane >> 4;
    const int t0 = 2 * wv, t1 = 2 * wv + 1;       // output-channel tiles per wave

    // zero yT agent-pad (cols 16..31) once; never overwritten (avoids 0*NaN)
    for (int i = t; i < 128 * 16; i += 256)
        yT[(i >> 4) * 40 + 16 + (i & 15)] = 0;

    // ---- all weight fragments -> registers (once per block, reused SPB times) ----
    short8 wr1[2][2], wo1[2][2], wr2[2][4], wo2[2][4], wh1f[8], wh2f[2], wh3f;
    #pragma unroll
    for (int i = 0; i < 2; ++i) {
        #pragma unroll
        for (int s = 0; s < 2; ++s) {
            wr1[i][s] = load_wfrag(Wrel1, 128, t0 + i, s, q, mrow);
            wo1[i][s] = load_wfrag(Wroot1, 128, t0 + i, s, q, mrow);
        }
        #pragma unroll
        for (int s = 0; s < 4; ++s) {
            wr2[i][s] = load_wfrag(Wrel2, 128, t0 + i, s, q, mrow);
            wo2[i][s] = load_wfrag(Wroot2, 128, t0 + i, s, q, mrow);
        }
    }
    #pragma unroll
    for (int s = 0; s < 8; ++s) wh1f[s] = load_wfrag(Wh1, 64, wv, s, q, mrow);
    #pragma unroll
    for (int s = 0; s < 2; ++s) wh2f[s] = load_wfrag(Wh2, 32, wv & 1, s, q, mrow);
    wh3f = load_wfrag(Wh3, 16, 0, 0, q, mrow);

    // biases (acc row = q*4+r -> channel tile*16 + q*4 + r)
    const float4 br1a = *(const float4*)(brel1 + t0 * 16 + q * 4);
    const float4 br1b = *(const float4*)(brel1 + t1 * 16 + q * 4);
    const float4 br2a = *(const float4*)(brel2 + t0 * 16 + q * 4);
    const float4 br2b = *(const float4*)(brel2 + t1 * 16 + q * 4);
    const float4 bb1  = *(const float4*)(bh1 + wv * 16 + q * 4);
    const float4 bb2  = *(const float4*)(bh2 + (wv & 1) * 16 + q * 4);
    const float4 bb3  = *(const float4*)(bh3 + q * 4);

    #pragma unroll 1
    for (int g = 0; g < SPB; ++g) {
        const size_t scene = (size_t)blockIdx.x * SPB + g;

        // ---- S0: stage x (f32 -> bf16) + adjacency masks ----
        {
            const int i0 = t * 4;
            const float4 v = *(const float4*)(x + scene * (NAG * 64) + i0);
            const unsigned p0 = (unsigned)f2b(v.x) | ((unsigned)f2b(v.y) << 16);
            const unsigned p1 = (unsigned)f2b(v.z) | ((unsigned)f2b(v.w) << 16);
            uint2 u; u.x = p0; u.y = p1;
            *(uint2*)&xb[(i0 >> 6) * 72 + (i0 & 63)] = u;
        }
        if (t < NAG) {
            const float* pp = pos + scene * (NAG * 2);
            const float ax = pp[2 * t], ay = pp[2 * t + 1];
            unsigned m = 0;
            for (int j = 0; j < NAG; ++j) {
                const float dx = ax - pp[2 * j], dy = ay - pp[2 * j + 1];
                if (dx * dx + dy * dy <= R2f && j != t) m |= (1u << j);
            }
            mask[t] = m;
        }
        __syncthreads();

        const short8 adjB = make_adjB(mask[mrow], q);   // reused by S2 and S4

        // ---- S1: y1^T = Wrel1^T @ x  -> yT ----
        {
            f32x4 a0 = {0.f, 0.f, 0.f, 0.f}, a1 = a0;
            #pragma unroll
            for (int s = 0; s < 2; ++s) {
                const short8 b = *(const short8*)&xb[mrow * 72 + s * 32 + q * 8];
                a0 = MFMA(wr1[0][s], b, a0);
                a1 = MFMA(wr1[1][s], b, a1);
            }
            #pragma unroll
            for (int r = 0; r < 4; ++r) {
                yT[(t0 * 16 + q * 4 + r) * 40 + mrow] = f2b(a0[r]);
                yT[(t1 * 16 + q * 4 + r) * 40 + mrow] = f2b(a1[r]);
            }
        }
        __syncthreads();

        // ---- S2: x1 = relu(adj@y1 + Wroot1^T@x + b1) -> x1b [agent][ch] ----
        {
            f32x4 a0 = {br1a.x, br1a.y, br1a.z, br1a.w};
            f32x4 a1 = {br1b.x, br1b.y, br1b.z, br1b.w};
            const short8 ya0 = *(const short8*)&yT[(t0 * 16 + mrow) * 40 + q * 8];
            const short8 ya1 = *(const short8*)&yT[(t1 * 16 + mrow) * 40 + q * 8];
            a0 = MFMA(ya0, adjB, a0);
            a1 = MFMA(ya1, adjB, a1);
            #pragma unroll
            for (int s = 0; s < 2; ++s) {
                const short8 b = *(const short8*)&xb[mrow * 72 + s * 32 + q * 8];
                a0 = MFMA(wo1[0][s], b, a0);
                a1 = MFMA(wo1[1][s], b, a1);
            }
            relu_store4(&x1b[mrow * 136 + t0 * 16 + q * 4], a0);
            relu_store4(&x1b[mrow * 136 + t1 * 16 + q * 4], a1);
        }
        __syncthreads();

        // ---- S3: y2^T = Wrel2^T @ x1 -> yT ----
        {
            f32x4 a0 = {0.f, 0.f, 0.f, 0.f}, a1 = a0;
            #pragma unroll
            for (int s = 0; s < 4; ++s) {
                const short8 b = *(const short8*)&x1b[mrow * 136 + s * 32 + q * 8];
                a0 = MFMA(wr2[0][s], b, a0);
                a1 = MFMA(wr2[1][s], b, a1);
            }
            #pragma unroll
            for (int r = 0; r < 4; ++r) {
                yT[(t0 * 16 + q * 4 + r) * 40 + mrow] = f2b(a0[r]);
                yT[(t1 * 16 + q * 4 + r) * 40 + mrow] = f2b(a1[r]);
            }
        }
        __syncthreads();

        // ---- S4: x2 = relu(adj@y2 + Wroot2^T@x1 + b2) -> x2b ----
        {
            f32x4 a0 = {br2a.x, br2a.y, br2a.z, br2a.w};
            f32x4 a1 = {br2b.x, br2b.y, br2b.z, br2b.w};
            const short8 ya0 = *(const short8*)&yT[(t0 * 16 + mrow) * 40 + q * 8];
            const short8 ya1 = *(const short8*)&yT[(t1 * 16 + mrow) * 40 + q * 8];
            a0 = MFMA(ya0, adjB, a0);
            a1 = MFMA(ya1, adjB, a1);
            #pragma unroll
            for (int s = 0; s < 4; ++s) {
                const short8 b = *(const short8*)&x1b[mrow * 136 + s * 32 + q * 8];
                a0 = MFMA(wo2[0][s], b, a0);
                a1 = MFMA(wo2[1][s], b, a1);
            }
            relu_store4(&x2b[mrow * 136 + t0 * 16 + q * 4], a0);
            relu_store4(&x2b[mrow * 136 + t1 * 16 + q * 4], a1);
        }
        __syncthreads();

        // ---- S5: h1 = relu(Wh1^T @ [x1|x2] + bh1), tile = wv -> h1b ----
        {
            f32x4 a = {bb1.x, bb1.y, bb1.z, bb1.w};
            #pragma unroll
            for (int s = 0; s < 8; ++s) {
                const short8 b = (s < 4)
                    ? *(const short8*)&x1b[mrow * 136 + s * 32 + q * 8]
                    : *(const short8*)&x2b[mrow * 136 + (s - 4) * 32 + q * 8];
                a = MFMA(wh1f[s], b, a);
            }
            relu_store4(&h1b[mrow * 72 + wv * 16 + q * 4], a);
        }
        __syncthreads();

        // ---- S6: h2 = relu(Wh2^T @ h1 + bh2), waves 0,1 -> h2b ----
        if (wv < 2) {
            f32x4 a = {bb2.x, bb2.y, bb2.z, bb2.w};
            #pragma unroll
            for (int s = 0; s < 2; ++s) {
                const short8 b = *(const short8*)&h1b[mrow * 72 + s * 32 + q * 8];
                a = MFMA(wh2f[s], b, a);
            }
            relu_store4(&h2b[mrow * 40 + wv * 16 + q * 4], a);
        }
        __syncthreads();

        // ---- S7: out = Wh3^T @ h2 + bh3, wave 0, f32 coalesced store ----
        if (wv == 0) {
            f32x4 a = {bb3.x, bb3.y, bb3.z, bb3.w};
            const short8 b = *(const short8*)&h2b[mrow * 40 + q * 8];
            a = MFMA(wh3f, b, a);
            float4 o; o.x = a[0]; o.y = a[1]; o.z = a[2]; o.w = a[3];
            *(float4*)(out + scene * (NAG * 16) + mrow * 16 + q * 4) = o;
        }
        // no barrier: next S0's barrier orders h2b reuse (wave 0 must pass it first)
    }
}

extern "C" void kernel_launch(void* const* d_in, const int* in_sizes, int n_in,
                              void* d_out, int out_size, void* d_ws, size_t ws_size,
                              hipStream_t stream) {
    const float* x      = (const float*)d_in[0];
    const float* pos    = (const float*)d_in[1];
    const float* Wrel1  = (const float*)d_in[2];
    const float* brel1  = (const float*)d_in[3];
    const float* Wroot1 = (const float*)d_in[4];
    const float* Wrel2  = (const float*)d_in[5];
    const float* brel2  = (const float*)d_in[6];
    const float* Wroot2 = (const float*)d_in[7];
    const float* Wh1    = (const float*)d_in[8];
    const float* bh1    = (const float*)d_in[9];
    const float* Wh2    = (const float*)d_in[10];
    const float* bh2    = (const float*)d_in[11];
    const float* Wh3    = (const float*)d_in[12];
    const float* bh3    = (const float*)d_in[13];

    gnn_fused2<<<NBLK, 256, 0, stream>>>(
        x, pos, Wrel1, brel1, Wroot1, Wrel2, brel2, Wroot2,
        Wh1, bh1, Wh2, bh2, Wh3, bh3, (float*)d_out);
}

// Round 6
// 149.447 us; speedup vs baseline: 1.6001x; 1.6001x over previous
//
#include <hip/hip_runtime.h>

#define NAG 16
#define SPB 8       // scenes per block
#define NBLK 1024   // 1024 * 8 = 8192 scenes; 4 blocks/CU resident at VGPR<=128
#define R2f 64.0f

typedef unsigned short u16;
typedef __attribute__((ext_vector_type(8))) short short8;
typedef __attribute__((ext_vector_type(4))) float f32x4;

#define MFMA(a, b, c) __builtin_amdgcn_mfma_f32_16x16x32_bf16(a, b, c, 0, 0, 0)

__device__ __forceinline__ u16 f2b(float f) {
    unsigned u = __float_as_uint(f);
    unsigned r = u + 0x7FFFu + ((u >> 16) & 1u);   // RNE
    return (u16)(r >> 16);
}

// A-fragment of W^T for output-channel tile `tile`, K-step `s` (32 input chans):
// element j <-> k = s*32 + q*8 + j, m = tile*16 + mrow; value = W[k][m] (W is [K][N] row-major)
__device__ __forceinline__ short8 load_wfrag(const float* __restrict__ W, int N,
                                             int tile, int s, int q, int mrow) {
    const float* p = W + (size_t)(s * 32 + q * 8) * N + tile * 16 + mrow;
    union { short8 v; unsigned u[4]; } r;
    #pragma unroll
    for (int jj = 0; jj < 4; ++jj) {
        const float f0 = p[(2 * jj) * N];
        const float f1 = p[(2 * jj + 1) * N];
        r.u[jj] = (unsigned)f2b(f0) | ((unsigned)f2b(f1) << 16);
    }
    return r.v;
}

// adjacency B-fragment: B[k][i], i = lane&15, k = q*8+j; adj[k][i] = bit k of mask[i]
// (adj symmetric). k >= 16 -> bits shift out -> exact 0.
__device__ __forceinline__ short8 make_adjB(unsigned m, int q) {
    union { short8 v; unsigned u[4]; } r;
    #pragma unroll
    for (int jj = 0; jj < 4; ++jj) {
        const int k0 = q * 8 + 2 * jj;              // <= 30
        const unsigned lo = ((m >> k0) & 1u) ? 0x3F80u : 0u;        // bf16 1.0
        const unsigned hi = ((m >> (k0 + 1)) & 1u) ? 0x3F80u : 0u;
        r.u[jj] = lo | (hi << 16);
    }
    return r.v;
}

__device__ __forceinline__ void relu_store4(u16* d, f32x4 a) {
    const unsigned p0 = (unsigned)f2b(fmaxf(a[0], 0.f)) | ((unsigned)f2b(fmaxf(a[1], 0.f)) << 16);
    const unsigned p1 = (unsigned)f2b(fmaxf(a[2], 0.f)) | ((unsigned)f2b(fmaxf(a[3], 0.f)) << 16);
    uint2 u; u.x = p0; u.y = p1;
    *(uint2*)d = u;   // 8B-aligned by construction at call sites
}

// NOTE: launch_bounds kept at (256,2) — R5 showed (256,4) caps VGPR at 64 and
// spills all weight fragments to scratch (FETCH 18.5->383 MB, dur 64->160us).
// At the natural VGPR=120, HW grants 4 waves/SIMD anyway; occupancy comes from
// the grid (1024 blocks = 4 resident blocks/CU).
__global__ __launch_bounds__(256, 2) void gnn_fused2(
    const float* __restrict__ x, const float* __restrict__ pos,
    const float* __restrict__ Wrel1, const float* __restrict__ brel1,
    const float* __restrict__ Wroot1,
    const float* __restrict__ Wrel2, const float* __restrict__ brel2,
    const float* __restrict__ Wroot2,
    const float* __restrict__ Wh1, const float* __restrict__ bh1,
    const float* __restrict__ Wh2, const float* __restrict__ bh2,
    const float* __restrict__ Wh3, const float* __restrict__ bh3,
    float* __restrict__ out)
{
    // padded row strides: +8 u16 (16B) keeps b128 rows on distinct bank groups
    __shared__ __align__(16) u16 xb[16 * 72];     // x   [agent][ch0..63]
    __shared__ __align__(16) u16 yT[128 * 40];    // y^T [channel][agent0..15 | 16..31 = zero pad]
    __shared__ __align__(16) u16 x1b[16 * 136];   // x1  [agent][ch0..127]
    __shared__ __align__(16) u16 x2b[16 * 136];   // x2
    __shared__ __align__(16) u16 h1b[16 * 72];    // h1  [agent][ch0..63]
    __shared__ __align__(16) u16 h2b[16 * 40];    // h2  [agent][ch0..31]
    __shared__ unsigned mask[NAG];

    const int t = threadIdx.x;
    const int wv = t >> 6;
    const int lane = t & 63;
    const int mrow = lane & 15;
    const int q = lane >> 4;
    const int t0 = 2 * wv, t1 = 2 * wv + 1;       // output-channel tiles per wave

    // zero yT agent-pad (cols 16..31) once; never overwritten (avoids 0*NaN)
    for (int i = t; i < 128 * 16; i += 256)
        yT[(i >> 4) * 40 + 16 + (i & 15)] = 0;

    // ---- all weight fragments -> registers (once per block, reused SPB times) ----
    short8 wr1[2][2], wo1[2][2], wr2[2][4], wo2[2][4], wh1f[8], wh2f[2], wh3f;
    #pragma unroll
    for (int i = 0; i < 2; ++i) {
        #pragma unroll
        for (int s = 0; s < 2; ++s) {
            wr1[i][s] = load_wfrag(Wrel1, 128, t0 + i, s, q, mrow);
            wo1[i][s] = load_wfrag(Wroot1, 128, t0 + i, s, q, mrow);
        }
        #pragma unroll
        for (int s = 0; s < 4; ++s) {
            wr2[i][s] = load_wfrag(Wrel2, 128, t0 + i, s, q, mrow);
            wo2[i][s] = load_wfrag(Wroot2, 128, t0 + i, s, q, mrow);
        }
    }
    #pragma unroll
    for (int s = 0; s < 8; ++s) wh1f[s] = load_wfrag(Wh1, 64, wv, s, q, mrow);
    #pragma unroll
    for (int s = 0; s < 2; ++s) wh2f[s] = load_wfrag(Wh2, 32, wv & 1, s, q, mrow);
    wh3f = load_wfrag(Wh3, 16, 0, 0, q, mrow);

    // biases (acc row = q*4+r -> channel tile*16 + q*4 + r)
    const float4 br1a = *(const float4*)(brel1 + t0 * 16 + q * 4);
    const float4 br1b = *(const float4*)(brel1 + t1 * 16 + q * 4);
    const float4 br2a = *(const float4*)(brel2 + t0 * 16 + q * 4);
    const float4 br2b = *(const float4*)(brel2 + t1 * 16 + q * 4);
    const float4 bb1  = *(const float4*)(bh1 + wv * 16 + q * 4);
    const float4 bb2  = *(const float4*)(bh2 + (wv & 1) * 16 + q * 4);
    const float4 bb3  = *(const float4*)(bh3 + q * 4);

    #pragma unroll 1
    for (int g = 0; g < SPB; ++g) {
        const size_t scene = (size_t)blockIdx.x * SPB + g;

        // ---- S0: stage x (f32 -> bf16) + adjacency masks ----
        {
            const int i0 = t * 4;
            const float4 v = *(const float4*)(x + scene * (NAG * 64) + i0);
            const unsigned p0 = (unsigned)f2b(v.x) | ((unsigned)f2b(v.y) << 16);
            const unsigned p1 = (unsigned)f2b(v.z) | ((unsigned)f2b(v.w) << 16);
            uint2 u; u.x = p0; u.y = p1;
            *(uint2*)&xb[(i0 >> 6) * 72 + (i0 & 63)] = u;
        }
        if (t < NAG) {
            const float* pp = pos + scene * (NAG * 2);
            const float ax = pp[2 * t], ay = pp[2 * t + 1];
            unsigned m = 0;
            for (int j = 0; j < NAG; ++j) {
                const float dx = ax - pp[2 * j], dy = ay - pp[2 * j + 1];
                if (dx * dx + dy * dy <= R2f && j != t) m |= (1u << j);
            }
            mask[t] = m;
        }
        __syncthreads();

        const short8 adjB = make_adjB(mask[mrow], q);   // reused by S2 and S4

        // ---- S1: y1^T = Wrel1^T @ x  -> yT ----
        {
            f32x4 a0 = {0.f, 0.f, 0.f, 0.f}, a1 = a0;
            #pragma unroll
            for (int s = 0; s < 2; ++s) {
                const short8 b = *(const short8*)&xb[mrow * 72 + s * 32 + q * 8];
                a0 = MFMA(wr1[0][s], b, a0);
                a1 = MFMA(wr1[1][s], b, a1);
            }
            #pragma unroll
            for (int r = 0; r < 4; ++r) {
                yT[(t0 * 16 + q * 4 + r) * 40 + mrow] = f2b(a0[r]);
                yT[(t1 * 16 + q * 4 + r) * 40 + mrow] = f2b(a1[r]);
            }
        }
        __syncthreads();

        // ---- S2: x1 = relu(adj@y1 + Wroot1^T@x + b1) -> x1b [agent][ch] ----
        {
            f32x4 a0 = {br1a.x, br1a.y, br1a.z, br1a.w};
            f32x4 a1 = {br1b.x, br1b.y, br1b.z, br1b.w};
            const short8 ya0 = *(const short8*)&yT[(t0 * 16 + mrow) * 40 + q * 8];
            const short8 ya1 = *(const short8*)&yT[(t1 * 16 + mrow) * 40 + q * 8];
            a0 = MFMA(ya0, adjB, a0);
            a1 = MFMA(ya1, adjB, a1);
            #pragma unroll
            for (int s = 0; s < 2; ++s) {
                const short8 b = *(const short8*)&xb[mrow * 72 + s * 32 + q * 8];
                a0 = MFMA(wo1[0][s], b, a0);
                a1 = MFMA(wo1[1][s], b, a1);
            }
            relu_store4(&x1b[mrow * 136 + t0 * 16 + q * 4], a0);
            relu_store4(&x1b[mrow * 136 + t1 * 16 + q * 4], a1);
        }
        __syncthreads();

        // ---- S3: y2^T = Wrel2^T @ x1 -> yT ----
        {
            f32x4 a0 = {0.f, 0.f, 0.f, 0.f}, a1 = a0;
            #pragma unroll
            for (int s = 0; s < 4; ++s) {
                const short8 b = *(const short8*)&x1b[mrow * 136 + s * 32 + q * 8];
                a0 = MFMA(wr2[0][s], b, a0);
                a1 = MFMA(wr2[1][s], b, a1);
            }
            #pragma unroll
            for (int r = 0; r < 4; ++r) {
                yT[(t0 * 16 + q * 4 + r) * 40 + mrow] = f2b(a0[r]);
                yT[(t1 * 16 + q * 4 + r) * 40 + mrow] = f2b(a1[r]);
            }
        }
        __syncthreads();

        // ---- S4: x2 = relu(adj@y2 + Wroot2^T@x1 + b2) -> x2b ----
        {
            f32x4 a0 = {br2a.x, br2a.y, br2a.z, br2a.w};
            f32x4 a1 = {br2b.x, br2b.y, br2b.z, br2b.w};
            const short8 ya0 = *(const short8*)&yT[(t0 * 16 + mrow) * 40 + q * 8];
            const short8 ya1 = *(const short8*)&yT[(t1 * 16 + mrow) * 40 + q * 8];
            a0 = MFMA(ya0, adjB, a0);
            a1 = MFMA(ya1, adjB, a1);
            #pragma unroll
            for (int s = 0; s < 4; ++s) {
                const short8 b = *(const short8*)&x1b[mrow * 136 + s * 32 + q * 8];
                a0 = MFMA(wo2[0][s], b, a0);
                a1 = MFMA(wo2[1][s], b, a1);
            }
            relu_store4(&x2b[mrow * 136 + t0 * 16 + q * 4], a0);
            relu_store4(&x2b[mrow * 136 + t1 * 16 + q * 4], a1);
        }
        __syncthreads();

        // ---- S5: h1 = relu(Wh1^T @ [x1|x2] + bh1), tile = wv -> h1b ----
        {
            f32x4 a = {bb1.x, bb1.y, bb1.z, bb1.w};
            #pragma unroll
            for (int s = 0; s < 8; ++s) {
                const short8 b = (s < 4)
                    ? *(const short8*)&x1b[mrow * 136 + s * 32 + q * 8]
                    : *(const short8*)&x2b[mrow * 136 + (s - 4) * 32 + q * 8];
                a = MFMA(wh1f[s], b, a);
            }
            relu_store4(&h1b[mrow * 72 + wv * 16 + q * 4], a);
        }
        __syncthreads();

        // ---- S6: h2 = relu(Wh2^T @ h1 + bh2), waves 0,1 -> h2b ----
        if (wv < 2) {
            f32x4 a = {bb2.x, bb2.y, bb2.z, bb2.w};
            #pragma unroll
            for (int s = 0; s < 2; ++s) {
                const short8 b = *(const short8*)&h1b[mrow * 72 + s * 32 + q * 8];
                a = MFMA(wh2f[s], b, a);
            }
            relu_store4(&h2b[mrow * 40 + wv * 16 + q * 4], a);
        }
        __syncthreads();

        // ---- S7: out = Wh3^T @ h2 + bh3, wave 0, f32 coalesced store ----
        if (wv == 0) {
            f32x4 a = {bb3.x, bb3.y, bb3.z, bb3.w};
            const short8 b = *(const short8*)&h2b[mrow * 40 + q * 8];
            a = MFMA(wh3f, b, a);
            float4 o; o.x = a[0]; o.y = a[1]; o.z = a[2]; o.w = a[3];
            *(float4*)(out + scene * (NAG * 16) + mrow * 16 + q * 4) = o;
        }
        // no barrier: next S0's barrier orders h2b reuse (wave 0 must pass it first)
    }
}

extern "C" void kernel_launch(void* const* d_in, const int* in_sizes, int n_in,
                              void* d_out, int out_size, void* d_ws, size_t ws_size,
                              hipStream_t stream) {
    const float* x      = (const float*)d_in[0];
    const float* pos    = (const float*)d_in[1];
    const float* Wrel1  = (const float*)d_in[2];
    const float* brel1  = (const float*)d_in[3];
    const float* Wroot1 = (const float*)d_in[4];
    const float* Wrel2  = (const float*)d_in[5];
    const float* brel2  = (const float*)d_in[6];
    const float* Wroot2 = (const float*)d_in[7];
    const float* Wh1    = (const float*)d_in[8];
    const float* bh1    = (const float*)d_in[9];
    const float* Wh2    = (const float*)d_in[10];
    const float* bh2    = (const float*)d_in[11];
    const float* Wh3    = (const float*)d_in[12];
    const float* bh3    = (const float*)d_in[13];

    gnn_fused2<<<NBLK, 256, 0, stream>>>(
        x, pos, Wrel1, brel1, Wroot1, Wrel2, brel2, Wroot2,
        Wh1, bh1, Wh2, bh2, Wh3, bh3, (float*)d_out);
}